// Round 2
// baseline (429.327 us; speedup 1.0000x reference)
//
#include <hip/hip_runtime.h>
#include <hip/hip_bf16.h>

#define B_    16
#define CIN   64
#define Hn    64
#define Wn    64
#define HID   128
#define SXS2  72    // sX2 row stride in shorts (144B, 16B-aligned)
#define SHS   136   // sH  row stride in shorts (272B, 16B-aligned)
#define NJC   8     // j-chunks per batch (16 channels each)
#define NBLK  (B_ * NJC)

typedef _Float16 h8_t __attribute__((ext_vector_type(8)));   // 8 fp16 (4 VGPRs)
typedef __attribute__((ext_vector_type(4))) float f4_t;

// d_ws layout:
//   [0, 256KB)        : h_buf[0]  fp16-encoded [16][64][128]  (b, w, ci), value = sgn*(h+2)
//   [256KB, 512KB)    : h_buf[1]  (row h writes buf[h&1]; phase sign = (h>>1)&1)
// No flags, no counters: readers poll the data words themselves (self-validating).
#define HBUF_SHORTS (B_ * Wn * HID)
#define HBUF_BYTES  (HBUF_SHORTS * 2)

static __device__ __forceinline__ float sigm(float z)  { return 1.f / (1.f + __expf(-z)); }
static __device__ __forceinline__ float tanhf_(float z){ return 2.f / (1.f + __expf(-2.f * z)) - 1.f; }

// lgkm-only barrier: does NOT drain vmcnt (keeps prefetches/stores in flight).
#define BAR_LGKM() do { \
    asm volatile("s_waitcnt lgkmcnt(0)" ::: "memory"); \
    __builtin_amdgcn_s_barrier(); \
    __builtin_amdgcn_sched_barrier(0); \
} while (0)

extern "C" __global__ __launch_bounds__(256, 1)
void rowlstm_kernel(const float* __restrict__ x,
                    const float* __restrict__ w_is,
                    const float* __restrict__ b_is,
                    const float* __restrict__ w_ss,
                    const float* __restrict__ b_ss,
                    float* __restrict__ out,
                    unsigned char* __restrict__ ws)
{
    const int tid  = threadIdx.x;
    const int bid  = blockIdx.x;
    const int b    = bid & 15;        // batch; same-b blocks share bid%8 -> same XCD (perf heuristic only)
    const int jc   = bid >> 4;        // j-chunk: channels [jc*16, jc*16+16)
    const int lane = tid & 63;
    const int wv   = tid >> 6;        // wave id = N-tile (16 w's)
    const int l15  = lane & 15;
    const int quad = lane >> 4;

    short* hbuf0 = (short*)ws;

    // LDS ~27 KB. Shifted-read panels: tap t of column w' reads row w'+t.
    __shared__ alignas(16) short sH[66 * SHS];    // h panel (ENCODED fp16), rows 0..65 (0,65 = guards)
    __shared__ alignas(16) short sX2[65 * SXS2];  // x panel fp16, rows 0..64 (0 = zero guard)
    __shared__ float sS3[4][16];                  // per (gate, ch-local) sum of fp16 h-weights

    // ---- A (weight) fragments, fp16, gate-major: M-row = mt*16 + l15 -> gate mt, ch l15.
    // K layout (512): [0,64) x kw0 | [64,128) x kw1 | [128,256) h kw0 | [256,384) h kw1 | [384,512) h kw2
    h8_t a_frag[4][16];
    #pragma unroll
    for (int mt = 0; mt < 4; ++mt) {
        const int co = mt * HID + jc * 16 + l15;
        #pragma unroll
        for (int kt = 0; kt < 16; ++kt) {
            const int kk0 = kt * 32 + quad * 8;
            const float* p;
            if      (kt < 2)  p = &w_is[(co * CIN + kk0)         * 3 + 0];
            else if (kt < 4)  p = &w_is[(co * CIN + (kk0 - 64))  * 3 + 1];
            else if (kt < 8)  p = &w_ss[(co * HID + (kk0 - 128)) * 3 + 0];
            else if (kt < 12) p = &w_ss[(co * HID + (kk0 - 256)) * 3 + 1];
            else              p = &w_ss[(co * HID + (kk0 - 384)) * 3 + 2];
            h8_t v;
            #pragma unroll
            for (int j = 0; j < 8; ++j) v[j] = (_Float16)p[j * 3];
            a_frag[mt][kt] = v;
        }
    }

    // ---- S3[g][ch] = sum of this channel's fp16 h-weights (kt 4..15), for offset correction.
    #pragma unroll
    for (int mt = 0; mt < 4; ++mt) {
        float s = 0.f;
        #pragma unroll
        for (int kt = 4; kt < 16; ++kt) {
            #pragma unroll
            for (int j = 0; j < 8; ++j) s += (float)a_frag[mt][kt][j];
        }
        s += __shfl_xor(s, 16);
        s += __shfl_xor(s, 32);     // now all quads of this l15 have the full row-sum
        if (wv == 0 && quad == 0) sS3[mt][l15] = s;
    }

    // zero guard row for x panel (true zero, never touched again)
    {
        h8_t z8 = {0,0,0,0,0,0,0,0};
        if (tid < 8) *(h8_t*)&sX2[tid * 8] = z8;
    }
    __syncthreads();

    // per-thread combined bias: b_is + b_ss - 2*S3  (the -2*S3 cancels the +2 encoding offset)
    float bias2[4][4];
    #pragma unroll
    for (int g = 0; g < 4; ++g) {
        #pragma unroll
        for (int r = 0; r < 4; ++r) {
            const int co = g * HID + jc * 16 + quad * 4 + r;
            bias2[g][r] = b_is[co] + b_ss[co] - 2.f * sS3[g][quad * 4 + r];
        }
    }

    float creg[4] = {0.f, 0.f, 0.f, 0.f};
    const int wp  = wv * 16 + l15;    // this thread's w (GEMM col and phase C)

    // x staging: thread (xw, xc2) holds x[ci = xc2*16 .. +15][xw] for the current row
    const int xw  = tid & 63;
    const int xc2 = tid >> 6;
    float xr[16];
    #pragma unroll
    for (int e = 0; e < 16; ++e)
        xr[e] = x[((b * CIN + xc2 * 16 + e) * Hn + 0) * Wn + xw];

    const int cig = tid & 15;     // 8-channel group (x2 halves of 8B)
    const int w0  = tid >> 4;     // base w for panel staging

    for (int h = 0; h < Hn; ++h) {
        const int p_read  = (h > 0) ? (((h - 1) >> 1) & 1) : 0;
        const int p_store = (h >> 1) & 1;
        const unsigned short psign = (unsigned short)(p_read << 15);

        const short* rd_hb = hbuf0 + ((h & 1) ^ 1) * HBUF_SHORTS + b * Wn * HID;
        short*       wr_hb = hbuf0 + (h & 1) * HBUF_SHORTS + b * Wn * HID;

        // ---- guard rows of sH: encoded zero = sgn*2.0 for the phase being read ----
        {
            const unsigned long long g = p_read ? 0xC000C000C000C000ULL : 0x4000400040004000ULL;
            if (tid < 16) {
                *(unsigned long long*)&sH[tid * 8]     = g;
                *(unsigned long long*)&sH[tid * 8 + 4] = g;
            } else if (tid < 32) {
                const int t = tid - 16;
                *(unsigned long long*)&sH[65 * SHS + t * 8]     = g;
                *(unsigned long long*)&sH[65 * SHS + t * 8 + 4] = g;
            }
        }

        // ---- issue first round of h-panel poll loads (fire), or fill for h==0 ----
        unsigned long long qv[8];
        unsigned need = 0;
        if (h > 0) {
            need = 0xFFu;
            #pragma unroll
            for (int it = 0; it < 8; ++it) {
                const int w = w0 + (it >> 1) * 16;
                qv[it] = __hip_atomic_load(
                    (const unsigned long long*)(rd_hb + w * HID + cig * 8 + (it & 1) * 4),
                    __ATOMIC_RELAXED, __HIP_MEMORY_SCOPE_AGENT);
            }
        } else {
            const unsigned long long fillv = 0x4000400040004000ULL;  // enc(+phase0, h=0)
            #pragma unroll
            for (int it = 0; it < 8; ++it) {
                const int w = w0 + (it >> 1) * 16;
                *(unsigned long long*)&sH[(w + 1) * SHS + cig * 8 + (it & 1) * 4] = fillv;
            }
        }

        // ---- build x panel (fp16) from xr prefetched last row ----
        {
            h8_t v0, v1;
            #pragma unroll
            for (int e = 0; e < 8; ++e) { v0[e] = (_Float16)xr[e]; v1[e] = (_Float16)xr[e + 8]; }
            *(h8_t*)&sX2[(xw + 1) * SXS2 + xc2 * 16]     = v0;
            *(h8_t*)&sX2[(xw + 1) * SXS2 + xc2 * 16 + 8] = v1;
        }

        BAR_LGKM();   // S1a: sX2 + sH guards ready (h-poll loads still in flight)

        // ---- x-GEMM (K=128) while the poll loads fly ----
        f4_t ax0 = {0,0,0,0}, ax1 = {0,0,0,0}, ax2 = {0,0,0,0}, ax3 = {0,0,0,0};
        #pragma unroll
        for (int kt = 0; kt < 4; ++kt) {
            const short* src = &sX2[(wp + (kt >> 1)) * SXS2 + (kt & 1) * 32 + quad * 8];
            h8_t bf = *(const h8_t*)src;
            ax0 = __builtin_amdgcn_mfma_f32_16x16x32_f16(a_frag[0][kt], bf, ax0, 0, 0, 0);
            ax1 = __builtin_amdgcn_mfma_f32_16x16x32_f16(a_frag[1][kt], bf, ax1, 0, 0, 0);
            ax2 = __builtin_amdgcn_mfma_f32_16x16x32_f16(a_frag[2][kt], bf, ax2, 0, 0, 0);
            ax3 = __builtin_amdgcn_mfma_f32_16x16x32_f16(a_frag[3][kt], bf, ax3, 0, 0, 0);
        }

        // ---- poll/validate/store-to-LDS loop (self-validating data sync) ----
        while (need) {
            #pragma unroll
            for (int it = 0; it < 8; ++it) {
                if (need & (1u << it)) {
                    const unsigned long long q = qv[it];
                    const unsigned short e = (unsigned short)q ^ psign;
                    if (e >= 0x3C00u && e <= 0x4200u) {     // |val| in [1,3] with expected sign
                        const int w = w0 + (it >> 1) * 16;
                        *(unsigned long long*)&sH[(w + 1) * SHS + cig * 8 + (it & 1) * 4] = q;
                        need &= ~(1u << it);
                    }
                }
            }
            if (!need) break;
            __builtin_amdgcn_s_sleep(1);
            #pragma unroll
            for (int it = 0; it < 8; ++it) {
                if (need & (1u << it)) {
                    const int w = w0 + (it >> 1) * 16;
                    qv[it] = __hip_atomic_load(
                        (const unsigned long long*)(rd_hb + w * HID + cig * 8 + (it & 1) * 4),
                        __ATOMIC_RELAXED, __HIP_MEMORY_SCOPE_AGENT);
                }
            }
        }

        BAR_LGKM();   // S1b: sH panel ready

        // ---- h-GEMM (K=384) on ENCODED values ----
        f4_t ah0 = {0,0,0,0}, ah1 = {0,0,0,0}, ah2 = {0,0,0,0}, ah3 = {0,0,0,0};
        #pragma unroll
        for (int kt = 4; kt < 16; ++kt) {
            const short* src = &sH[(wp + ((kt - 4) >> 2)) * SHS + ((kt - 4) & 3) * 32 + quad * 8];
            h8_t bf = *(const h8_t*)src;
            ah0 = __builtin_amdgcn_mfma_f32_16x16x32_f16(a_frag[0][kt], bf, ah0, 0, 0, 0);
            ah1 = __builtin_amdgcn_mfma_f32_16x16x32_f16(a_frag[1][kt], bf, ah1, 0, 0, 0);
            ah2 = __builtin_amdgcn_mfma_f32_16x16x32_f16(a_frag[2][kt], bf, ah2, 0, 0, 0);
            ah3 = __builtin_amdgcn_mfma_f32_16x16x32_f16(a_frag[3][kt], bf, ah3, 0, 0, 0);
        }

        // ---- phase C: z = z_x + sgn*acc_h + (bias - 2*S3); fully lane-local ----
        float hv[4];
        #pragma unroll
        for (int r = 0; r < 4; ++r) {
            const float h0v = p_read ? -ah0[r] : ah0[r];
            const float h1v = p_read ? -ah1[r] : ah1[r];
            const float h2v = p_read ? -ah2[r] : ah2[r];
            const float h3v = p_read ? -ah3[r] : ah3[r];
            float ig = sigm (ax0[r] + h0v + bias2[0][r]);
            float fg = sigm (ax1[r] + h1v + bias2[1][r]);
            float og = sigm (ax2[r] + h2v + bias2[2][r]);
            float gg = tanhf_(ax3[r] + h3v + bias2[3][r]);
            float c  = fg * creg[r] + ig * gg;
            creg[r]  = c;
            hv[r]    = og * tanhf_(c);
            out[((b * HID + jc * 16 + quad * 4 + r) * Hn + h) * Wn + wp] = hv[r];
        }
        // ---- encoded h store: sgn*(h+2), 4x fp16 packed, fire-and-forget ----
        {
            unsigned long long pk = 0;
            #pragma unroll
            for (int r = 0; r < 4; ++r) {
                float ef = hv[r] + 2.f;
                if (p_store) ef = -ef;
                union { _Float16 f; unsigned short s; } u;
                u.f = (_Float16)ef;
                pk |= ((unsigned long long)u.s) << (16 * r);
            }
            __hip_atomic_store((unsigned long long*)(wr_hb + wp * HID + jc * 16 + quad * 4),
                               pk, __ATOMIC_RELAXED, __HIP_MEMORY_SCOPE_AGENT);
        }
        // ---- prefetch next row's x (fire-and-forget; consumed after next poll) ----
        {
            const int hp = (h < Hn - 1) ? h + 1 : h;
            #pragma unroll
            for (int e = 0; e < 16; ++e)
                xr[e] = x[((b * CIN + xc2 * 16 + e) * Hn + hp) * Wn + xw];
        }

        BAR_LGKM();   // S2: all LDS reads done; panels rebuildable next row (no vm drain!)
    }
}

extern "C" void kernel_launch(void* const* d_in, const int* in_sizes, int n_in,
                              void* d_out, int out_size, void* d_ws, size_t ws_size,
                              hipStream_t stream) {
    const float* x    = (const float*)d_in[0];
    const float* w_is = (const float*)d_in[1];
    const float* b_is = (const float*)d_in[2];
    const float* w_ss = (const float*)d_in[3];
    const float* b_ss = (const float*)d_in[4];
    float* out = (float*)d_out;
    unsigned char* ws = (unsigned char*)d_ws;

    // zero both h buffers: 0x0000 fails both validity windows
    hipMemsetAsync(ws, 0, 2 * HBUF_BYTES, stream);

    // 128 blocks (8 j-chunks x 16 batches), ~27KB LDS, 1 block/CU -> all co-resident.
    rowlstm_kernel<<<dim3(NBLK), dim3(256), 0, stream>>>(x, w_is, b_is, w_ss, b_ss, out, ws);
}

// Round 3
// 321.167 us; speedup vs baseline: 1.3368x; 1.3368x over previous
//
#include <hip/hip_runtime.h>
#include <hip/hip_bf16.h>

#define B_    16
#define CIN   64
#define Hn    64
#define Wn    64
#define HID   128
#define SXS2  72    // sX2 row stride in shorts (144B, 16B-aligned)
#define SHS   136   // sH  row stride in shorts (272B, 16B-aligned)
#define NJC   8     // j-chunks per batch (16 channels each)
#define NBLK  (B_ * NJC)

typedef __attribute__((ext_vector_type(8))) short bfrag_t;   // 8 bf16 (4 VGPRs)
typedef __attribute__((ext_vector_type(4))) float f4_t;

// d_ws layout:
//   [0, 256KB)        : h_buf[0]  bf16 [16][64][128]   (b, w, ci)
//   [256KB, 512KB)    : h_buf[1]  (step h writes buf[h&1], reads buf[h&1^1])
//   [512KB, +4KB)     : per-b flag line (256B): flags[jc] = rows completed by block (b,jc)
#define HBUF_SHORTS (B_ * Wn * HID)
#define HBUF_BYTES  (HBUF_SHORTS * 2)
#define FLG_STRIDE  256

static __device__ __forceinline__ short f2bf(float f) {
    union { __hip_bfloat16 h; short s; } u;
    u.h = __float2bfloat16(f);
    return u.s;
}
static __device__ __forceinline__ float sigm(float z)  { return 1.f / (1.f + __expf(-z)); }
static __device__ __forceinline__ float tanhf_(float z){ return 2.f / (1.f + __expf(-2.f * z)) - 1.f; }

// lgkm-only barrier: does NOT drain vmcnt (keeps global loads/stores in flight).
// asm "memory" clobber = compiler fence (atomics can't be hoisted across it);
// sched_barrier(0) pins the MIR scheduler (guideline 18).
#define BAR_LGKM() do { \
    asm volatile("s_waitcnt lgkmcnt(0)" ::: "memory"); \
    __builtin_amdgcn_s_barrier(); \
    __builtin_amdgcn_sched_barrier(0); \
} while (0)

// vm-drain barrier: waits store-ack (coherence point) for this wave's stores, then syncs block.
#define BAR_VM() do { \
    asm volatile("s_waitcnt vmcnt(0)" ::: "memory"); \
    __builtin_amdgcn_s_barrier(); \
    __builtin_amdgcn_sched_barrier(0); \
} while (0)

extern "C" __global__ __launch_bounds__(256, 1)
void rowlstm_kernel(const float* __restrict__ x,
                    const float* __restrict__ w_is,
                    const float* __restrict__ b_is,
                    const float* __restrict__ w_ss,
                    const float* __restrict__ b_ss,
                    float* __restrict__ out,
                    unsigned char* __restrict__ ws)
{
    const int tid  = threadIdx.x;
    const int bid  = blockIdx.x;
    const int b    = bid & 15;        // batch; same-b blocks share bid%8 -> same XCD (perf heuristic only)
    const int jc   = bid >> 4;        // j-chunk: channels [jc*16, jc*16+16)
    const int lane = tid & 63;
    const int wv   = tid >> 6;        // wave id = N-tile (16 w's)
    const int l15  = lane & 15;
    const int quad = lane >> 4;

    short*    hbuf0 = (short*)ws;
    unsigned* flags = (unsigned*)(ws + 2 * HBUF_BYTES + b * FLG_STRIDE);  // 8 words, one 32B region

    // LDS ~27 KB. Shifted-read panels: tap t of column w' reads row w'+t.
    __shared__ alignas(16) short sH[66 * SHS];    // h panel, rows 0..65 (0,65 = zero guards)
    __shared__ alignas(16) short sX2[65 * SXS2];  // x panel, rows 0..64 (0 = zero guard)

    // ---- A (weight) fragments, gate-major: M-row = mt*16 + l15 -> gate mt, ch l15.
    // K layout (512): [0,64) x kw0 | [64,128) x kw1 | [128,256) h kw0 | [256,384) h kw1 | [384,512) h kw2
    bfrag_t a_frag[4][16];
    #pragma unroll
    for (int mt = 0; mt < 4; ++mt) {
        const int co = mt * HID + jc * 16 + l15;
        #pragma unroll
        for (int kt = 0; kt < 16; ++kt) {
            const int kk0 = kt * 32 + quad * 8;   // region constant per (kt,quad): boundaries are 32-aligned
            const float* p;
            if      (kt < 2)  p = &w_is[(co * CIN + kk0)         * 3 + 0];
            else if (kt < 4)  p = &w_is[(co * CIN + (kk0 - 64))  * 3 + 1];
            else if (kt < 8)  p = &w_ss[(co * HID + (kk0 - 128)) * 3 + 0];
            else if (kt < 12) p = &w_ss[(co * HID + (kk0 - 256)) * 3 + 1];
            else              p = &w_ss[(co * HID + (kk0 - 384)) * 3 + 2];
            bfrag_t v;
            #pragma unroll
            for (int j = 0; j < 8; ++j) v[j] = f2bf(p[j * 3]);
            a_frag[mt][kt] = v;
        }
    }

    // per-thread biases: 4 gates x 4 channels (this thread's channels = quad*4 + r)
    float bias[4][4];
    #pragma unroll
    for (int g = 0; g < 4; ++g) {
        #pragma unroll
        for (int r = 0; r < 4; ++r) {
            const int co = g * HID + jc * 16 + quad * 4 + r;
            bias[g][r] = b_is[co] + b_ss[co];
        }
    }

    // zero guard rows (never touched again)
    {
        bfrag_t z8 = {0,0,0,0,0,0,0,0};
        if (tid < 8)  *(bfrag_t*)&sX2[tid * 8] = z8;                 // sX2 row 0 (64 ci)
        if (tid < 16) {
            *(bfrag_t*)&sH[tid * 8] = z8;                            // sH row 0
            *(bfrag_t*)&sH[65 * SHS + tid * 8] = z8;                 // sH row 65
        }
    }

    float creg[4] = {0.f, 0.f, 0.f, 0.f};
    const int wp  = wv * 16 + l15;    // this thread's w (GEMM col and phase C)

    // x staging: thread (xw, xc2) holds x[ci = xc2*16 .. +15][xw] for the current row
    const int xw  = tid & 63;
    const int xc2 = tid >> 6;
    float xr[16];
    #pragma unroll
    for (int e = 0; e < 16; ++e)
        xr[e] = x[((b * CIN + xc2 * 16 + e) * Hn + 0) * Wn + xw];

    const int cig = tid & 15;     // 8-ch group within panel staging
    const int w0  = tid >> 4;     // base w for panel staging

    __syncthreads();

    for (int h = 0; h < Hn; ++h) {
        const short* rd_hb = hbuf0 + ((h & 1) ^ 1) * HBUF_SHORTS + b * Wn * HID;
        short*       wr_hb = hbuf0 + (h & 1) * HBUF_SHORTS + b * Wn * HID;

        // ---- single-wave poll: wave 0 checks all 8 flags (one coalesced 32B load / round) ----
        if (h > 0 && wv == 0) {
            const unsigned tgt = (unsigned)h;
            for (;;) {
                unsigned f = tgt;
                if (lane < NJC)
                    f = __hip_atomic_load(&flags[lane], __ATOMIC_RELAXED, __HIP_MEMORY_SCOPE_AGENT);
                if (__all((int)(f >= tgt))) break;
            }
        }
        BAR_LGKM();   // release: all blocks of batch b finished row h-1; panels reusable

        // ---- issue h-panel loads immediately (latency hidden under x-panel build + x-GEMM) ----
        union { bfrag_t f; unsigned long long q[2]; } hu0, hu1, hu2, hu3;
        if (h > 0) {
            const unsigned long long* s0 = (const unsigned long long*)(rd_hb + (w0     ) * HID + cig * 8);
            const unsigned long long* s1 = (const unsigned long long*)(rd_hb + (w0 + 16) * HID + cig * 8);
            const unsigned long long* s2 = (const unsigned long long*)(rd_hb + (w0 + 32) * HID + cig * 8);
            const unsigned long long* s3 = (const unsigned long long*)(rd_hb + (w0 + 48) * HID + cig * 8);
            hu0.q[0] = __hip_atomic_load(s0,     __ATOMIC_RELAXED, __HIP_MEMORY_SCOPE_AGENT);
            hu0.q[1] = __hip_atomic_load(s0 + 1, __ATOMIC_RELAXED, __HIP_MEMORY_SCOPE_AGENT);
            hu1.q[0] = __hip_atomic_load(s1,     __ATOMIC_RELAXED, __HIP_MEMORY_SCOPE_AGENT);
            hu1.q[1] = __hip_atomic_load(s1 + 1, __ATOMIC_RELAXED, __HIP_MEMORY_SCOPE_AGENT);
            hu2.q[0] = __hip_atomic_load(s2,     __ATOMIC_RELAXED, __HIP_MEMORY_SCOPE_AGENT);
            hu2.q[1] = __hip_atomic_load(s2 + 1, __ATOMIC_RELAXED, __HIP_MEMORY_SCOPE_AGENT);
            hu3.q[0] = __hip_atomic_load(s3,     __ATOMIC_RELAXED, __HIP_MEMORY_SCOPE_AGENT);
            hu3.q[1] = __hip_atomic_load(s3 + 1, __ATOMIC_RELAXED, __HIP_MEMORY_SCOPE_AGENT);
        } else {
            hu0.q[0] = hu0.q[1] = 0ull; hu1.q[0] = hu1.q[1] = 0ull;
            hu2.q[0] = hu2.q[1] = 0ull; hu3.q[0] = hu3.q[1] = 0ull;
        }

        // ---- build x panel (row h) from xr prefetched last row ----
        {
            bfrag_t v0, v1;
            #pragma unroll
            for (int e = 0; e < 8; ++e) { v0[e] = f2bf(xr[e]); v1[e] = f2bf(xr[e + 8]); }
            *(bfrag_t*)&sX2[(xw + 1) * SXS2 + xc2 * 16]     = v0;
            *(bfrag_t*)&sX2[(xw + 1) * SXS2 + xc2 * 16 + 8] = v1;
        }
        BAR_LGKM();   // S1a: sX2 ready (h-loads still in flight)

        // ---- x-GEMM (kt 0..3) under the h-load latency ----
        f4_t acc0 = {0.f,0.f,0.f,0.f}, acc1 = {0.f,0.f,0.f,0.f};
        f4_t acc2 = {0.f,0.f,0.f,0.f}, acc3 = {0.f,0.f,0.f,0.f};
        #pragma unroll
        for (int kt = 0; kt < 4; ++kt) {
            const short* src = &sX2[(wp + (kt >> 1)) * SXS2 + (kt & 1) * 32 + quad * 8];
            bfrag_t bf = *(const bfrag_t*)src;
            acc0 = __builtin_amdgcn_mfma_f32_16x16x32_bf16(a_frag[0][kt], bf, acc0, 0, 0, 0);
            acc1 = __builtin_amdgcn_mfma_f32_16x16x32_bf16(a_frag[1][kt], bf, acc1, 0, 0, 0);
            acc2 = __builtin_amdgcn_mfma_f32_16x16x32_bf16(a_frag[2][kt], bf, acc2, 0, 0, 0);
            acc3 = __builtin_amdgcn_mfma_f32_16x16x32_bf16(a_frag[3][kt], bf, acc3, 0, 0, 0);
        }

        // ---- h panel writes (compiler inserts the precise vmcnt for hu*) ----
        *(bfrag_t*)&sH[(w0 +  1) * SHS + cig * 8] = hu0.f;
        *(bfrag_t*)&sH[(w0 + 17) * SHS + cig * 8] = hu1.f;
        *(bfrag_t*)&sH[(w0 + 33) * SHS + cig * 8] = hu2.f;
        *(bfrag_t*)&sH[(w0 + 49) * SHS + cig * 8] = hu3.f;
        BAR_LGKM();   // S1b: sH ready

        // ---- h-GEMM (kt 4..15), accumulate into the same accs ----
        #pragma unroll
        for (int kt = 4; kt < 16; ++kt) {
            const short* src = &sH[(wp + ((kt - 4) >> 2)) * SHS + ((kt - 4) & 3) * 32 + quad * 8];
            bfrag_t bf = *(const bfrag_t*)src;
            acc0 = __builtin_amdgcn_mfma_f32_16x16x32_bf16(a_frag[0][kt], bf, acc0, 0, 0, 0);
            acc1 = __builtin_amdgcn_mfma_f32_16x16x32_bf16(a_frag[1][kt], bf, acc1, 0, 0, 0);
            acc2 = __builtin_amdgcn_mfma_f32_16x16x32_bf16(a_frag[2][kt], bf, acc2, 0, 0, 0);
            acc3 = __builtin_amdgcn_mfma_f32_16x16x32_bf16(a_frag[3][kt], bf, acc3, 0, 0, 0);
        }

        // ---- phase C: fully lane-local. acc_g[r] = z[gate g][ch quad*4+r][w=wp] ----
        float hv[4];
        #pragma unroll
        for (int r = 0; r < 4; ++r) {
            float ig = sigm (acc0[r] + bias[0][r]);
            float fg = sigm (acc1[r] + bias[1][r]);
            float og = sigm (acc2[r] + bias[2][r]);
            float gg = tanhf_(acc3[r] + bias[3][r]);
            float c  = fg * creg[r] + ig * gg;
            creg[r]  = c;
            hv[r]    = og * tanhf_(c);
        }

        // ---- h-store FIRST, minimal drain, then one-way flag (chain-critical path) ----
        if (h + 1 < Hn) {
            unsigned p0 = (unsigned)(unsigned short)f2bf(hv[0]) |
                          ((unsigned)(unsigned short)f2bf(hv[1]) << 16);
            unsigned p1 = (unsigned)(unsigned short)f2bf(hv[2]) |
                          ((unsigned)(unsigned short)f2bf(hv[3]) << 16);
            unsigned long long pk = (unsigned long long)p0 | ((unsigned long long)p1 << 32);
            __hip_atomic_store((unsigned long long*)(wr_hb + wp * HID + jc * 16 + quad * 4),
                               pk, __ATOMIC_RELAXED, __HIP_MEMORY_SCOPE_AGENT);
            BAR_VM();   // only the fresh h-stores are outstanding here (out/prefetch long retired)
            if (tid == 0)
                __hip_atomic_store(&flags[jc], (unsigned)(h + 1),
                                   __ATOMIC_RELAXED, __HIP_MEMORY_SCOPE_AGENT);
        }

        // ---- off-chain work: out-stores + next-row x prefetch (never gate a barrier) ----
        #pragma unroll
        for (int r = 0; r < 4; ++r)
            out[((b * HID + jc * 16 + quad * 4 + r) * Hn + h) * Wn + wp] = hv[r];

        if (h + 1 < Hn) {
            #pragma unroll
            for (int e = 0; e < 16; ++e)
                xr[e] = x[((b * CIN + xc2 * 16 + e) * Hn + (h + 1)) * Wn + xw];
        }
    }
}

extern "C" void kernel_launch(void* const* d_in, const int* in_sizes, int n_in,
                              void* d_out, int out_size, void* d_ws, size_t ws_size,
                              hipStream_t stream) {
    const float* x    = (const float*)d_in[0];
    const float* w_is = (const float*)d_in[1];
    const float* b_is = (const float*)d_in[2];
    const float* w_ss = (const float*)d_in[3];
    const float* b_ss = (const float*)d_in[4];
    float* out = (float*)d_out;
    unsigned char* ws = (unsigned char*)d_ws;

    hipMemsetAsync(ws + 2 * HBUF_BYTES, 0, B_ * FLG_STRIDE, stream);

    // 128 blocks (8 j-chunks x 16 batches), ~27KB LDS, 1 block/CU -> all co-resident.
    rowlstm_kernel<<<dim3(NBLK), dim3(256), 0, stream>>>(x, w_is, b_is, w_ss, b_ss, out, ws);
}